// Round 3
// baseline (13175.209 us; speedup 1.0000x reference)
//
#include <hip/hip_runtime.h>
#include <math.h>

// Problem dims (fixed)
#define Bv   4
#define Sv   512
#define Hv   1024
#define Nv   128
#define Lv   6
#define Vv   32000
#define NHv  8
#define FFv  4096
#define DHv  128
#define Mv   (Bv*Sv)   // 2048 token rows

typedef unsigned short u16;

// bf16 (as ushort) <-> fp32
__device__ __forceinline__ float b2f(u16 u) {
    union { unsigned int i; float f; } v; v.i = ((unsigned int)u) << 16; return v.f;
}
__device__ __forceinline__ u16 f2b(float f) {
    union { float f; unsigned int i; } v; v.f = f;
    unsigned int x = v.i;
    return (u16)((x + 0x7fffu + ((x >> 16) & 1u)) >> 16);   // RNE
}

// ---------------------------------------------------------------------------
// On-device dtype probe. Reads the first 512 shorts (1 KB) of the tensor —
// in-bounds whether the buffer is bf16 (n*2 B, n>=768 min here) or fp32.
// fp32 data: short pairs look like (random mantissa half, sane exponent half);
// bf16 data: every short is a sane bf16 value. All-zero data -> bf16 path
// (reads fewer bytes = always safe; decodes 0.0 = correct either way).
// Requires blockDim >= 128; sh = 2 dedicated shared ints. Returns 1 if bf16.
// ---------------------------------------------------------------------------
__device__ __forceinline__ int sane16(u16 u) {
    if (u == 0) return 1;
    int e = (u >> 7) & 0xFF;
    return (e >= 0x66 && e <= 0x8F);   // |v| roughly in [1e-7, 1e5]
}
__device__ __forceinline__ int probe_bf16(const void* base, int* sh) {
    int t = threadIdx.x;
    if (t == 0) { sh[0] = 0; sh[1] = 0; }
    __syncthreads();
    if (t < 128) {
        ushort4 v = ((const ushort4*)base)[t];          // shorts [4t..4t+3]
        int nz = (v.x != 0) + (v.y != 0) + (v.z != 0) + (v.w != 0);
        int fp = ((sane16(v.y) && (v.x == 0 || !sane16(v.x))) ? 1 : 0)
               + ((sane16(v.w) && (v.z == 0 || !sane16(v.z))) ? 1 : 0);
        if (nz) atomicAdd(&sh[1], nz);
        if (fp) atomicAdd(&sh[0], fp);
    }
    __syncthreads();
    int fpcnt = sh[0], nzcnt = sh[1];
    if (nzcnt == 0) return 1;          // all-zero: safe/correct as bf16
    return (fpcnt < 128) ? 1 : 0;      // >=128 of 256 fp32-like pairs -> fp32
}
__device__ __forceinline__ float ld_in(const void* base, long idx, int isbf) {
    return isbf ? b2f(((const u16*)base)[idx]) : ((const float*)base)[idx];
}

// ---------------------------------------------------------------------------
// Embedding: x[b,s,:] = emb[ids[b,s],:] + pos[s,:]
// ---------------------------------------------------------------------------
__global__ __launch_bounds__(256) void k_embed(const int* __restrict__ ids,
                                               const void* __restrict__ emb,
                                               const void* __restrict__ pos,
                                               float* __restrict__ x) {
    __shared__ int psh[4];
    int ef = probe_bf16(emb, &psh[0]);
    int pf = probe_bf16(pos, &psh[2]);
    int row = blockIdx.x;
    int s   = row & (Sv - 1);
    long eb = (long)ids[row] * Hv;
    long pb = (long)s * Hv;
    float* o = x + (size_t)row * Hv;
    for (int h = threadIdx.x; h < Hv; h += 256)
        o[h] = ld_in(emb, eb + h, ef) + ld_in(pos, pb + h, pf);
}

// ---------------------------------------------------------------------------
// Tiled SGEMM: C[M,N] = A[M,K] @ W[N,K]^T (+bias) (+exact GELU if epi==1)
// A fp32 scratch. W/bias are INPUT tensors (dtype probed at base).
// to_out: if 1 and W is bf16, store bf16 (output dtype == policy dtype).
// Tiles 64x64x16, 256 threads, 4x4 acc/thread. M,N %64==0, K %16==0.
// ---------------------------------------------------------------------------
__global__ __launch_bounds__(256) void k_gemm(const float* __restrict__ A,
                                              const void* __restrict__ Wb, long Woff,
                                              const void* __restrict__ Bb, long Boff,
                                              int has_bias,
                                              float* __restrict__ C,
                                              int M, int N, int K, int epi, int to_out) {
    __shared__ float As[64][17];   // +1 pad breaks power-of-2 bank stride
    __shared__ float Ws[64][17];
    __shared__ int psh[4];
    int wf = probe_bf16(Wb, &psh[0]);
    int bfl = has_bias ? probe_bf16(Bb, &psh[2]) : 0;

    const int bm = blockIdx.y * 64, bn = blockIdx.x * 64;
    const int tx = threadIdx.x & 15, ty = threadIdx.x >> 4;
    const int lr = threadIdx.x >> 2;          // 0..63 (tile row to load)
    const int lk = (threadIdx.x & 3) << 2;    // 0,4,8,12
    const float* Ap = A + (size_t)(bm + lr) * K + lk;
    const long   wr = Woff + (long)(bn + lr) * K + lk;
    const float* Wp32 = (const float*)Wb + wr;
    const u16*   Wp16 = (const u16*)Wb + wr;
    float acc[4][4] = {};
    for (int k0 = 0; k0 < K; k0 += 16) {
        float4 av = *(const float4*)(Ap + k0);
        float w0, w1, w2, w3;
        if (wf) { ushort4 wv = *(const ushort4*)(Wp16 + k0);
                  w0 = b2f(wv.x); w1 = b2f(wv.y); w2 = b2f(wv.z); w3 = b2f(wv.w); }
        else    { float4 wv = *(const float4*)(Wp32 + k0);
                  w0 = wv.x; w1 = wv.y; w2 = wv.z; w3 = wv.w; }
        As[lr][lk+0] = av.x; As[lr][lk+1] = av.y; As[lr][lk+2] = av.z; As[lr][lk+3] = av.w;
        Ws[lr][lk+0] = w0;   Ws[lr][lk+1] = w1;   Ws[lr][lk+2] = w2;   Ws[lr][lk+3] = w3;
        __syncthreads();
#pragma unroll
        for (int k = 0; k < 16; ++k) {
            float a[4], w[4];
#pragma unroll
            for (int i = 0; i < 4; ++i) a[i] = As[ty*4+i][k];
#pragma unroll
            for (int j = 0; j < 4; ++j) w[j] = Ws[tx*4+j][k];
#pragma unroll
            for (int i = 0; i < 4; ++i)
#pragma unroll
                for (int j = 0; j < 4; ++j) acc[i][j] = fmaf(a[i], w[j], acc[i][j]);
        }
        __syncthreads();
    }
#pragma unroll
    for (int i = 0; i < 4; ++i) {
        int row = bm + ty*4 + i;
#pragma unroll
        for (int j = 0; j < 4; ++j) {
            int col = bn + tx*4 + j;
            float v = acc[i][j];
            if (has_bias) v += ld_in(Bb, Boff + col, bfl);
            if (epi == 1) v = 0.5f * v * (1.f + erff(v * 0.70710678118654752f));
            size_t idx = (size_t)row * N + col;
            if (to_out && wf) ((u16*)C)[idx] = f2b(v);
            else              C[idx] = v;
        }
    }
}

// ---------------------------------------------------------------------------
// u = sigmoid(gpre) * ub   (elementwise fp32 scratch)
// ---------------------------------------------------------------------------
__global__ __launch_bounds__(256) void k_gate(const float* __restrict__ gpre,
                                              const float* __restrict__ ub,
                                              float* __restrict__ u, int n) {
    int i = blockIdx.x * 256 + threadIdx.x;
    if (i < n) {
        float s = 1.f / (1.f + expf(-gpre[i]));
        u[i] = s * ub[i];
    }
}

// ---------------------------------------------------------------------------
// Selective-scan: st[b,s,n] = A[n]*st[b,s-1,n] + u[b,s,n],  A = exp(A_log)
// grid = B blocks, 128 threads (coalesced over n).
// ---------------------------------------------------------------------------
__global__ __launch_bounds__(128) void k_scan(const void* __restrict__ A_log, long off,
                                              const float* __restrict__ u,
                                              float* __restrict__ st) {
    __shared__ int psh[2];
    int af = probe_bf16(A_log, psh);
    int b = blockIdx.x, n = threadIdx.x;
    float A = expf(ld_in(A_log, off + n, af));
    const float* up = u  + (size_t)b * Sv * Nv + n;
    float*       sp = st + (size_t)b * Sv * Nv + n;
    float s = 0.f;
    for (int t = 0; t < Sv; ++t) {
        s = fmaf(A, s, up[(size_t)t * Nv]);
        sp[(size_t)t * Nv] = s;
    }
}

// ---------------------------------------------------------------------------
// y += (Dp[h]+1) * x   (fuses Dp*x from SSM + the residual "+x" before LN)
// ---------------------------------------------------------------------------
__global__ __launch_bounds__(256) void k_dx(float* __restrict__ y,
                                            const float* __restrict__ x,
                                            const void* __restrict__ Dp, long off) {
    __shared__ int psh[2];
    int df = probe_bf16(Dp, psh);
    int row = blockIdx.x;
    size_t base = (size_t)row * Hv;
    for (int h = threadIdx.x; h < Hv; h += 256)
        y[base + h] = fmaf(ld_in(Dp, off + h, df) + 1.f, x[base + h], y[base + h]);
}

// ---------------------------------------------------------------------------
// LayerNorm: out = postscale * ( LN(a (+ b)) * g + beta ), H=1024, eps=1e-5.
// a/b/out fp32 scratch; g/beta input tensors (probed). In-place safe.
// ---------------------------------------------------------------------------
__global__ __launch_bounds__(256) void k_ln(const float* __restrict__ a,
                                            const float* __restrict__ b,
                                            const void* __restrict__ g, long goff,
                                            const void* __restrict__ bb, long boff,
                                            float* __restrict__ out,
                                            float postscale) {
    __shared__ float buf[Hv];
    __shared__ float red[4];
    __shared__ int psh[4];
    int gf_ = probe_bf16(g, &psh[0]);
    int bf_ = probe_bf16(bb, &psh[2]);
    int row = blockIdx.x, t = threadIdx.x;
    const float* ap = a + (size_t)row * Hv;
    const float* bp = b ? b + (size_t)row * Hv : nullptr;
    float ls = 0.f;
    for (int h = t; h < Hv; h += 256) {
        float v = ap[h] + (bp ? bp[h] : 0.f);
        buf[h] = v; ls += v;
    }
#pragma unroll
    for (int o = 32; o > 0; o >>= 1) ls += __shfl_down(ls, o, 64);
    if ((t & 63) == 0) red[t >> 6] = ls;
    __syncthreads();
    float mu = (red[0] + red[1] + red[2] + red[3]) * (1.f / Hv);
    __syncthreads();
    float lv = 0.f;
    for (int h = t; h < Hv; h += 256) { float d = buf[h] - mu; lv += d * d; }
#pragma unroll
    for (int o = 32; o > 0; o >>= 1) lv += __shfl_down(lv, o, 64);
    if ((t & 63) == 0) red[t >> 6] = lv;
    __syncthreads();
    float rstd = rsqrtf((red[0] + red[1] + red[2] + red[3]) * (1.f / Hv) + 1e-5f);
    for (int h = t; h < Hv; h += 256)
        out[(size_t)row * Hv + h] =
            ((buf[h] - mu) * rstd * ld_in(g, goff + h, gf_) + ld_in(bb, boff + h, bf_)) * postscale;
}

// ---------------------------------------------------------------------------
// Fused attention: one block per (b, head, q-row), 128 threads.
// qkv [B,S,3H] fp32 scratch; q|k|v at col offsets 0|H|2H, head h at +h*DH.
// ---------------------------------------------------------------------------
__global__ __launch_bounds__(128) void k_attn(const float* __restrict__ qkv,
                                              float* __restrict__ ao) {
    __shared__ float qs[DHv];
    __shared__ float att[Sv];
    __shared__ float redm[2], reds[2];
    int q = blockIdx.x, h = blockIdx.y, b = blockIdx.z;
    int t = threadIdx.x;
    const size_t rs = 3 * (size_t)Hv;
    const float* qp = qkv + ((size_t)b * Sv + q) * rs + h * DHv;
    const float* kp = qkv + (size_t)b * Sv * rs + Hv     + h * DHv;
    const float* vp = qkv + (size_t)b * Sv * rs + 2 * Hv + h * DHv;

    qs[t] = qp[t] * 0.08838834764831845f;   // 1/sqrt(128)
    __syncthreads();

    float lmax = -1e30f;
    for (int k = t; k < Sv; k += 128) {
        const float4* kr = (const float4*)(kp + (size_t)k * rs);
        const float4* q4 = (const float4*)qs;
        float d = 0.f;
#pragma unroll
        for (int j = 0; j < DHv / 4; ++j) {
            float4 kv = kr[j], qv = q4[j];
            d += qv.x * kv.x + qv.y * kv.y + qv.z * kv.z + qv.w * kv.w;
        }
        att[k] = d;
        lmax = fmaxf(lmax, d);
    }
#pragma unroll
    for (int o = 32; o > 0; o >>= 1) lmax = fmaxf(lmax, __shfl_down(lmax, o, 64));
    if ((t & 63) == 0) redm[t >> 6] = lmax;
    __syncthreads();
    float m = fmaxf(redm[0], redm[1]);

    float lsum = 0.f;
    for (int k = t; k < Sv; k += 128) {
        float e = expf(att[k] - m);
        att[k] = e; lsum += e;
    }
#pragma unroll
    for (int o = 32; o > 0; o >>= 1) lsum += __shfl_down(lsum, o, 64);
    if ((t & 63) == 0) reds[t >> 6] = lsum;
    __syncthreads();
    float inv = 1.f / (reds[0] + reds[1]);

    float o = 0.f;
    for (int k = 0; k < Sv; ++k)
        o = fmaf(att[k], vp[(size_t)k * rs + t], o);
    ao[((size_t)b * Sv + q) * Hv + h * DHv + t] = o * inv;
}

// ---------------------------------------------------------------------------
extern "C" void kernel_launch(void* const* d_in, const int* in_sizes, int n_in,
                              void* d_out, int out_size, void* d_ws, size_t ws_size,
                              hipStream_t stream) {
    const int*  ids   = (const int*)d_in[0];
    const void *emb = d_in[1], *pos = d_in[2], *A_log = d_in[3], *WB = d_in[4],
               *WC = d_in[5], *Dp = d_in[6], *Wg = d_in[7], *bg = d_in[8],
               *Wout = d_in[9], *bout = d_in[10], *gs = d_in[11], *bs = d_in[12],
               *Wqkv = d_in[13], *bqkv = d_in[14], *Wo = d_in[15], *bo = d_in[16],
               *W1 = d_in[17], *b1 = d_in[18], *W2 = d_in[19], *b2 = d_in[20],
               *g1 = d_in[21], *bn1 = d_in[22], *g2 = d_in[23], *bn2 = d_in[24],
               *g3 = d_in[25], *bn3 = d_in[26], *gf = d_in[27], *bf = d_in[28];

    // Scratch: front 56 MB of d_out (dead before the final GEMM overwrites all
    // of d_out; d_out >= 131 MB under either output dtype). FINAL (read while
    // d_out is written) lives in d_ws: 8 MB, proven in-bounds in round 2.
    char* ob = (char*)d_out;
    float* X   = (float*)(ob + 0);          //  8 MB  [2048,1024]
    float* T1  = (float*)(ob + 8388608);    //  8 MB  [2048,1024]
    float* T2  = (float*)(ob + 16777216);   //  8 MB  [2048,1024]
    float* FH  = (float*)(ob + 25165824);   // 32 MB  [2048,4096]
    float* QKV = FH;                        // 24 MB  [2048,3072]  (aliased)
    float* G   = FH;                        //  1 MB  [2048,128]   (aliased)
    float* U   = (float*)(ob + 25165824 + 1048576);
    float* ST  = (float*)(ob + 25165824 + 2097152);
    float* FINAL = (float*)d_ws;            //  8 MB  [2048,1024]

    auto gemm = [&](const float* A, const void* W, long Woff, const void* bias, long Boff,
                    int hasb, float* C, int M, int N, int K, int epi, int to_out) {
        dim3 grid(N / 64, M / 64);
        k_gemm<<<grid, 256, 0, stream>>>(A, W, Woff, bias, Boff, hasb, C, M, N, K, epi, to_out);
    };

    k_embed<<<Mv, 256, 0, stream>>>(ids, emb, pos, X);

    for (int i = 0; i < Lv; ++i) {
        long oNH = (long)i * Nv * Hv, oHN = (long)i * Hv * Nv, oHH = (long)i * Hv * Hv;
        long oN = (long)i * Nv, oH = (long)i * Hv;

        // --- SSM block ---
        gemm(X, Wg, oNH, bg, oN, 1, G, Mv, Nv, Hv, 0, 0);           // gate pre-act
        gemm(X, WB, oNH, nullptr, 0, 0, U, Mv, Nv, Hv, 0, 0);       // B proj
        k_gate<<<(Mv * Nv) / 256, 256, 0, stream>>>(G, U, U, Mv * Nv);
        k_scan<<<Bv, 128, 0, stream>>>(A_log, oN, U, ST);
        gemm(ST, WC, oHN, nullptr, 0, 0, T1, Mv, Hv, Nv, 0, 0);     // y = st @ WC^T
        k_dx<<<Mv, 256, 0, stream>>>(T1, X, Dp, oH);                // += (Dp+1)*x
        k_ln<<<Mv, 256, 0, stream>>>(T1, nullptr, gs, oH, bs, oH, T2, 1.f);
        gemm(T2, Wout, oHH, bout, oH, 1, T1, Mv, Hv, Hv, 0, 0);     // xs
        k_ln<<<Mv, 256, 0, stream>>>(X, T1, g1, oH, bn1, oH, X, 1.f);

        // --- attention (odd layers); HierarchicalMemory x2 folds into LN postscale ---
        if (i & 1) {
            gemm(X, Wqkv, 3 * oHH, bqkv, 3 * oH, 1, QKV, Mv, 3 * Hv, Hv, 0, 0);
            dim3 ag(Sv, NHv, Bv);
            k_attn<<<ag, 128, 0, stream>>>(QKV, T1);
            gemm(T1, Wo, oHH, bo, oH, 1, T2, Mv, Hv, Hv, 0, 0);
            k_ln<<<Mv, 256, 0, stream>>>(X, T2, g2, oH, bn2, oH, X, 2.f);
        } else {
            k_ln<<<Mv, 256, 0, stream>>>(X, nullptr, g2, oH, bn2, oH, X, 2.f);
        }

        // --- FFN ---
        gemm(X, W1, (long)i * FFv * Hv, b1, (long)i * FFv, 1, FH, Mv, FFv, Hv, 1, 0);
        gemm(FH, W2, (long)i * Hv * FFv, b2, oH, 1, T1, Mv, Hv, FFv, 0, 0);
        k_ln<<<Mv, 256, 0, stream>>>(X, T1, g3, oH, bn3, oH, X, 1.f);
    }

    // --- final LN (into d_ws) + tied lm_head (dtype follows emb; fills d_out) ---
    k_ln<<<Mv, 256, 0, stream>>>(X, nullptr, gf, 0, bf, 0, FINAL, 1.f);
    gemm(FINAL, emb, 0, nullptr, 0, 0, (float*)d_out, Mv, Vv, Hv, 0, 1);
}